// Round 12
// baseline (61.251 us; speedup 1.0000x reference)
//
#include <hip/hip_runtime.h>

#define DD 2048
#define BB 16

typedef float f32x4 __attribute__((ext_vector_type(4)));
typedef short bf16x8 __attribute__((ext_vector_type(8)));

static __device__ inline short bfbits(float f) {
    __bf16 h = (__bf16)f;                      // compiles to v_cvt_pk_bf16_f32 pairs
    return __builtin_bit_cast(short, h);
}

static __device__ inline bf16x8 cvt8(f32x4 a, f32x4 b) {
    bf16x8 r;
#pragma unroll
    for (int e = 0; e < 4; ++e) {
        r[e]     = bfbits(a[e]);
        r[4 + e] = bfbits(b[e]);
    }
    return r;
}

// ---------------------------------------------------------------------------
// gemm v3: same dual-gate fused structure as R11, but 16 waves/block
// (1024 threads) with K-range 128 per wave -> 2x in-flight load bytes for
// latency hiding on the W stream. Block = 8 output columns.
// A-frag rows 0-7 = Wa[j0..j0+7], rows 8-15 = Wx[j0..j0+7]; B = xt.
// C/D layout (m89-verified): col = lane&15 (b), row = (lane>>4)*4 + reg.
// ---------------------------------------------------------------------------
__global__ __launch_bounds__(1024) void gemm_kernel(
    const float* __restrict__ xt, const float* __restrict__ h,
    const float* __restrict__ Wa, const float* __restrict__ Wx,
    const float* __restrict__ ba, const float* __restrict__ bx,
    const float* __restrict__ Lam,
    float* __restrict__ u_ws, float* __restrict__ dv_ws)
{
    const int j0   = blockIdx.x * 8;      // 256 blocks
    const int wv   = threadIdx.x >> 6;    // 0..15 : K-range
    const int lane = threadIdx.x & 63;
    const int mn   = lane & 15;
    const int kc   = lane >> 4;           // 0..3

    // rows 0-7: Wa; rows 8-15: Wx (same j-range)
    const float* wrow = (mn < 8) ? (Wa + (size_t)(j0 + mn) * DD)
                                 : (Wx + (size_t)(j0 + (mn & 7)) * DD);
    const float* xrow = xt + (size_t)mn * DD;
    const int kbase = wv * 128 + kc * 8;

    f32x4 acc = {0.f, 0.f, 0.f, 0.f};
#pragma unroll
    for (int s = 0; s < 4; ++s) {
        const int k = kbase + s * 32;
        const f32x4 wa0 = *(const f32x4*)(wrow + k);
        const f32x4 wa1 = *(const f32x4*)(wrow + k + 4);
        const f32x4 xb0 = *(const f32x4*)(xrow + k);
        const f32x4 xb1 = *(const f32x4*)(xrow + k + 4);
        acc = __builtin_amdgcn_mfma_f32_16x16x32_bf16(cvt8(wa0, wa1), cvt8(xb0, xb1), acc, 0, 0, 0);
    }

    __shared__ float part[16][256];
#pragma unroll
    for (int r = 0; r < 4; ++r) part[wv][lane * 4 + r] = acc[r];
    __syncthreads();

    __shared__ float comb[16][17];        // [row][b], padded
    if (threadIdx.x < 256) {
        const int t = threadIdx.x;
        float s = 0.f;
#pragma unroll
        for (int w = 0; w < 16; ++w) s += part[w][t];
        const int l   = t >> 2;
        const int r   = t & 3;
        const int row = ((l >> 4) << 2) + r;   // 0..15: 0-7 A-gate, 8-15 X-gate
        const int col = l & 15;                // b
        comb[row][col] = s;
    }
    __syncthreads();

    if (threadIdx.x < 128) {
        const int b  = threadIdx.x >> 3;       // 0..15
        const int jr = threadIdx.x & 7;        // 0..7
        const int j  = j0 + jr;
        const float sA = comb[jr][b]     + ba[j];
        const float sX = comb[jr + 8][b] + bx[j];
        const float rt  = 1.f / (1.f + expf(-sA));
        const float itg = 1.f / (1.f + expf(-sX));
        const float log_a = -log1pf(expf(-Lam[j]));    // -softplus(-Lam)
        const float a = expf(log_a * rt * 0.125f);     // / C, C = 8
        const float u = sqrtf(fmaxf(0.f, 1.f - a * a)) * (itg * xt[b * DD + j]);
        const float dv = fmaf(a, h[b * DD + j], u);
        u_ws[b * DD + j]  = u;
        dv_ws[b * DD + j] = dv;
    }
}

// ---------------------------------------------------------------------------
// fill (unchanged — best measured): block = (b, 8 rows); u cached in regs,
// 16 coalesced float4 stores/thread, diagonal patched inline.
// ---------------------------------------------------------------------------
__global__ __launch_bounds__(256) void fill_kernel(
    const float4* __restrict__ u4, const float* __restrict__ dv,
    float4* __restrict__ out)
{
    const int blk = blockIdx.x;       // 0..4095
    const int b   = blk >> 8;         // 0..15
    const int ig  = blk & 255;        // 0..255
    const int i0  = ig << 3;          // 8 rows starting here
    const int t   = threadIdx.x;

    const float4 v0 = u4[(b << 9) + t];         // j4 = t
    const float4 v1 = u4[(b << 9) + 256 + t];   // j4 = 256 + t

    float4* orow = out + ((size_t)b << 20) + ((size_t)i0 << 9);
#pragma unroll
    for (int r = 0; r < 8; ++r) {
        const int i   = i0 + r;
        const int dj4 = i >> 2;
        float4 w0 = v0, w1 = v1;
        if (dj4 == t) {
            ((float*)&w0)[i & 3] = dv[(b << 11) + i];
        } else if (dj4 == 256 + t) {
            ((float*)&w1)[i & 3] = dv[(b << 11) + i];
        }
        orow[t]       = w0;
        orow[256 + t] = w1;
        orow += DD / 4;
    }
}

extern "C" void kernel_launch(void* const* d_in, const int* in_sizes, int n_in,
                              void* d_out, int out_size, void* d_ws, size_t ws_size,
                              hipStream_t stream) {
    const float* xt  = (const float*)d_in[0];
    const float* h   = (const float*)d_in[1];
    const float* Wa  = (const float*)d_in[2];
    const float* Wx  = (const float*)d_in[3];
    const float* ba  = (const float*)d_in[4];
    const float* bx  = (const float*)d_in[5];
    const float* Lam = (const float*)d_in[6];

    float* u_ws  = (float*)d_ws;          // [B, D]
    float* dv_ws = u_ws + BB * DD;        // [B, D]

    gemm_kernel<<<DD / 8, 1024, 0, stream>>>(xt, h, Wa, Wx, ba, bx, Lam, u_ws, dv_ws);
    fill_kernel<<<BB * (DD / 8), 256, 0, stream>>>((const float4*)u_ws, dv_ws, (float4*)d_out);
}